// Round 1
// baseline (17.117 us; speedup 1.0000x reference)
//
#include <hip/hip_runtime.h>

// LogLinearModel: logits[b,j,v] = bias[v] + sum_{p=0..3} W[v, x[b,j-4+p]*4 + p]  (j>=4)
//                 logits[b,j,v] = bias[v]                                        (j<4)
// B=32, L=4096, N_SYM=64, D=256. Output fp32 (B,L,64) = 32MB -> memory-bound.

#define NSYM   64
#define CTX    4            // n-1
#define DFEAT  256          // NSYM*CTX
#define LSEQ   4096
#define BATCH  32
#define NPOS   (BATCH * LSEQ)     // 131072 positions
#define NITER  (NPOS / 4)         // 32768 wave-iterations (4 positions/wave-iter)
#define ITERS_PER_WAVE 16
#define BLOCKS (NITER / (ITERS_PER_WAVE * 4))   // 512 blocks, 4 waves each

__global__ __launch_bounds__(256, 2)
void loglinear_kernel(const int* __restrict__ x,
                      const float* __restrict__ W,
                      const float* __restrict__ bias,
                      float* __restrict__ out) {
    // Swizzled transposed W: logical Wt[d][v], 256 rows x 64 cols fp32 = 64KB.
    // Physical float4-slot m within row d holds cols v = 4*(m ^ (d&15)) .. +3.
    __shared__ float wt[DFEAT * NSYM];

    const int t = threadIdx.x;

    // ---- stage: W (64x256 row-major) -> LDS transposed + XOR-swizzled ----
    // thread t: v = t&63 (lane-distinct -> conflict-free LDS writes, banks 2-way),
    // global reads are 16B scattered (stride 1KB across lanes) from L2 - one-time.
    {
        const int v = t & 63;
        const int chunk = t >> 6;          // 0..3
        #pragma unroll
        for (int it = 0; it < 16; ++it) {
            const int f4 = chunk * 16 + it;          // float4 index within W row
            const int d0 = f4 * 4;
            const float4 w = *reinterpret_cast<const float4*>(W + v * DFEAT + d0);
            const float wv[4] = {w.x, w.y, w.z, w.w};
            #pragma unroll
            for (int k = 0; k < 4; ++k) {
                const int d = d0 + k;
                const int addr = d * 64 + ((((v >> 2) ^ (d & 15)) << 2) | (v & 3));
                wt[addr] = wv[k];
            }
        }
    }
    __syncthreads();

    const int lane = t & 63;
    const int wave = t >> 6;
    const int g = lane >> 4;     // position sub-index within wave-iter (0..3)
    const int q = lane & 15;     // v-quad index (float4 of outputs)

    const float4 b4 = reinterpret_cast<const float4*>(bias)[q];

    const int gw = blockIdx.x * 4 + wave;      // global wave id, 0..2047
    const int i0 = gw * ITERS_PER_WAVE;        // contiguous chunk per wave
    float4* __restrict__ out4 = reinterpret_cast<float4*>(out);

    #pragma unroll 4
    for (int ii = 0; ii < ITERS_PER_WAVE; ++ii) {
        const int i = i0 + ii;
        const int P = i * 4 + g;               // global position index
        const int bi = P >> 12;                // / LSEQ
        const int j = P & (LSEQ - 1);
        float4 acc = b4;
        if (j >= CTX) {
            const int* xp = x + bi * LSEQ + j - CTX;
            #pragma unroll
            for (int p = 0; p < CTX; ++p) {
                const int c = xp[p] * 4 + p;   // W column index, 0..255
                const float4 w = *reinterpret_cast<const float4*>(
                    wt + c * 64 + ((q ^ (c & 15)) << 2));
                acc.x += w.x; acc.y += w.y; acc.z += w.z; acc.w += w.w;
            }
        }
        out4[(size_t)P * 16 + q] = acc;        // wave stores contiguous 1KB
    }
}

extern "C" void kernel_launch(void* const* d_in, const int* in_sizes, int n_in,
                              void* d_out, int out_size, void* d_ws, size_t ws_size,
                              hipStream_t stream) {
    const int*   x  = (const int*)d_in[0];     // (32,4096) symbols 0..63
    const float* W  = (const float*)d_in[1];   // (64,256) row-major
    const float* b  = (const float*)d_in[2];   // (64,)
    float*       out = (float*)d_out;          // (32,4096,64) fp32

    hipLaunchKernelGGL(loglinear_kernel, dim3(BLOCKS), dim3(256), 0, stream,
                       x, W, b, out);
}